// Round 21
// baseline (652.096 us; speedup 1.0000x reference)
//
#include <hip/hip_runtime.h>
#include <hip/hip_bf16.h>
#include <math.h>

#define CC 896
#define TT 512
#define BB 4
#define HH 14
#define NN 64
#define DD 64
#define DGG 160
#define FF4 3584
#define MM (BB*TT)   // 2048
#define NCH 16       // chunks per (b,h)
#define CL 32        // chunk length = TT/NCH

typedef __attribute__((ext_vector_type(8))) short bf16x8;
typedef __attribute__((ext_vector_type(4))) float f32x4;

__device__ __forceinline__ float waveRedSum(float x) {
#pragma unroll
  for (int off = 32; off > 0; off >>= 1) x += __shfl_xor(x, off, 64);
  return x;
}

__device__ __forceinline__ float sigmoidf_(float x) { return 1.f / (1.f + expf(-x)); }

__device__ __forceinline__ ushort bf16bits(float v) {
  __hip_bfloat16 h = __float2bfloat16(v);
  return *(ushort*)&h;
}

__device__ __forceinline__ void gload_lds16(const void* g, void* l) {
  __builtin_amdgcn_global_load_lds((const __attribute__((address_space(1))) void*)g,
                                   (__attribute__((address_space(3))) void*)l, 16, 0, 0);
}
__device__ __forceinline__ void gload_lds4(const void* g, void* l) {
  __builtin_amdgcn_global_load_lds((const __attribute__((address_space(1))) void*)g,
                                   (__attribute__((address_space(3))) void*)l, 4, 0, 0);
}

// ---------------- LayerNorm with idx gather (embedding + ln0) ----------------
__global__ __launch_bounds__(256)
void ln_kernel(const float* __restrict__ in, const int* __restrict__ idx,
               const float* __restrict__ w, const float* __restrict__ bvec,
               float* __restrict__ out)
{
  int m = blockIdx.x;
  const float* row = idx ? (in + (size_t)idx[m] * CC) : (in + (size_t)m * CC);
  float s = 0.f, s2 = 0.f;
  for (int c = threadIdx.x; c < CC; c += 256) { float x = row[c]; s += x; s2 += x * x; }
  __shared__ float red[2][4];
  float a = waveRedSum(s), b2 = waveRedSum(s2);
  int wid = threadIdx.x >> 6;
  if ((threadIdx.x & 63) == 0) { red[0][wid] = a; red[1][wid] = b2; }
  __syncthreads();
  s  = red[0][0] + red[0][1] + red[0][2] + red[0][3];
  s2 = red[1][0] + red[1][1] + red[1][2] + red[1][3];
  float mean = s * (1.f / CC);
  float var  = s2 * (1.f / CC) - mean * mean;
  float inv  = rsqrtf(var + 1e-5f);
  float* orow = out + (size_t)m * CC;
  for (int c = threadIdx.x; c < CC; c += 256)
    orow[c] = (row[c] - mean) * inv * w[c] + bvec[c];
}

// ---------------- final LN + head ----------------
__global__ __launch_bounds__(256)
void head_kernel(const float* __restrict__ x, const float* __restrict__ w,
                 const float* __restrict__ bvec, const float* __restrict__ hw,
                 float* __restrict__ out)
{
  int m = blockIdx.x;
  const float* row = x + (size_t)m * CC;
  float s = 0.f, s2 = 0.f;
  for (int c = threadIdx.x; c < CC; c += 256) { float v = row[c]; s += v; s2 += v * v; }
  __shared__ float red[2][4];
  float a = waveRedSum(s), b2 = waveRedSum(s2);
  int wid = threadIdx.x >> 6;
  if ((threadIdx.x & 63) == 0) { red[0][wid] = a; red[1][wid] = b2; }
  __syncthreads();
  s  = red[0][0] + red[0][1] + red[0][2] + red[0][3];
  s2 = red[1][0] + red[1][1] + red[1][2] + red[1][3];
  float mean = s * (1.f / CC);
  float var  = s2 * (1.f / CC) - mean * mean;
  float inv  = rsqrtf(var + 1e-5f);
  float p = 0.f;
  for (int c = threadIdx.x; c < CC; c += 256)
    p += ((row[c] - mean) * inv * w[c] + bvec[c]) * hw[c];
  p = waveRedSum(p);
  __shared__ float red2[4];
  if ((threadIdx.x & 63) == 0) red2[wid] = p;
  __syncthreads();
  if (threadIdx.x == 0) out[m] = red2[0] + red2[1] + red2[2] + red2[3];
}

// ---------------- fused LN + 6-way token-shift mix (time-mix entry) ----------------
__global__ __launch_bounds__(256)
void lnmix6_kernel(const float* __restrict__ x, const float* __restrict__ w,
                   const float* __restrict__ bvec,
                   const float* __restrict__ cr, const float* __restrict__ cw,
                   const float* __restrict__ ck, const float* __restrict__ cv,
                   const float* __restrict__ ca, const float* __restrict__ cg,
                   __hip_bfloat16* __restrict__ outr, __hip_bfloat16* __restrict__ outw,
                   __hip_bfloat16* __restrict__ outk, __hip_bfloat16* __restrict__ outv,
                   __hip_bfloat16* __restrict__ outa, __hip_bfloat16* __restrict__ outg)
{
  int m = blockIdx.x;
  int t = m % TT;
  const float* row  = x + (size_t)m * CC;
  const float* prow = row - CC;
  float s = 0.f, s2 = 0.f, sp = 0.f, sp2 = 0.f;
  for (int c = threadIdx.x; c < CC; c += 256) {
    float xv = row[c]; s += xv; s2 += xv * xv;
    if (t > 0) { float pv = prow[c]; sp += pv; sp2 += pv * pv; }
  }
  float a0 = waveRedSum(s), a1 = waveRedSum(s2), a2 = waveRedSum(sp), a3 = waveRedSum(sp2);
  __shared__ float red[4][4];
  int wid = threadIdx.x >> 6;
  if ((threadIdx.x & 63) == 0) { red[0][wid]=a0; red[1][wid]=a1; red[2][wid]=a2; red[3][wid]=a3; }
  __syncthreads();
  s   = red[0][0]+red[0][1]+red[0][2]+red[0][3];
  s2  = red[1][0]+red[1][1]+red[1][2]+red[1][3];
  sp  = red[2][0]+red[2][1]+red[2][2]+red[2][3];
  sp2 = red[3][0]+red[3][1]+red[3][2]+red[3][3];
  float mean = s * (1.f / CC);
  float inv  = rsqrtf(s2 * (1.f / CC) - mean * mean + 1e-5f);
  float meanp = sp * (1.f / CC);
  float invp  = rsqrtf(sp2 * (1.f / CC) - meanp * meanp + 1e-5f);
  for (int c = threadIdx.x; c < CC; c += 256) {
    float xnv = (row[c] - mean) * inv * w[c] + bvec[c];
    float xpv = (t > 0) ? (prow[c] - meanp) * invp * w[c] + bvec[c] : 0.f;
    float d = xpv - xnv;
    size_t off = (size_t)m * CC + c;
    outr[off] = __float2bfloat16(fmaf(d, cr[c], xnv));
    outw[off] = __float2bfloat16(fmaf(d, cw[c], xnv));
    outk[off] = __float2bfloat16(fmaf(d, ck[c], xnv));
    outv[off] = __float2bfloat16(fmaf(d, cv[c], xnv));
    outa[off] = __float2bfloat16(fmaf(d, ca[c], xnv));
    outg[off] = __float2bfloat16(fmaf(d, cg[c], xnv));
  }
}

// ---------------- fused LN + single mix (channel-mix entry) ----------------
__global__ __launch_bounds__(256)
void lnmixc_kernel(const float* __restrict__ x, const float* __restrict__ w,
                   const float* __restrict__ bvec, const float* __restrict__ coef,
                   __hip_bfloat16* __restrict__ outb)
{
  int m = blockIdx.x;
  int t = m % TT;
  const float* row  = x + (size_t)m * CC;
  const float* prow = row - CC;
  float s = 0.f, s2 = 0.f, sp = 0.f, sp2 = 0.f;
  for (int c = threadIdx.x; c < CC; c += 256) {
    float xv = row[c]; s += xv; s2 += xv * xv;
    if (t > 0) { float pv = prow[c]; sp += pv; sp2 += pv * pv; }
  }
  float a0 = waveRedSum(s), a1 = waveRedSum(s2), a2 = waveRedSum(sp), a3 = waveRedSum(sp2);
  __shared__ float red[4][4];
  int wid = threadIdx.x >> 6;
  if ((threadIdx.x & 63) == 0) { red[0][wid]=a0; red[1][wid]=a1; red[2][wid]=a2; red[3][wid]=a3; }
  __syncthreads();
  s   = red[0][0]+red[0][1]+red[0][2]+red[0][3];
  s2  = red[1][0]+red[1][1]+red[1][2]+red[1][3];
  sp  = red[2][0]+red[2][1]+red[2][2]+red[2][3];
  sp2 = red[3][0]+red[3][1]+red[3][2]+red[3][3];
  float mean = s * (1.f / CC);
  float inv  = rsqrtf(s2 * (1.f / CC) - mean * mean + 1e-5f);
  float meanp = sp * (1.f / CC);
  float invp  = rsqrtf(sp2 * (1.f / CC) - meanp * meanp + 1e-5f);
  for (int c = threadIdx.x; c < CC; c += 256) {
    float xnv = (row[c] - mean) * inv * w[c] + bvec[c];
    float xpv = (t > 0) ? (prow[c] - meanp) * invp * w[c] + bvec[c] : 0.f;
    outb[(size_t)m * CC + c] = __float2bfloat16(fmaf(xpv - xnv, coef[c], xnv));
  }
}

// ---------------- convert + transpose body ----------------
__device__ __forceinline__ void convT_body(const float* __restrict__ W,
                                           __hip_bfloat16* __restrict__ Wt,
                                           int K, int N, int KP, int NP,
                                           int bx, int by)
{
  __shared__ float tile[32][33];
  int bn = bx * 32, bk = by * 32;
  int tx = threadIdx.x & 31, ty = threadIdx.x >> 5;
#pragma unroll
  for (int i = 0; i < 4; i++) {
    int k = bk + ty + i * 8, n = bn + tx;
    tile[ty + i * 8][tx] = (k < K && n < N) ? W[(size_t)k * N + n] : 0.f;
  }
  __syncthreads();
#pragma unroll
  for (int i = 0; i < 4; i++) {
    int n = bn + ty + i * 8, k = bk + tx;
    if (n < NP && k < KP)
      Wt[(size_t)n * KP + k] = __float2bfloat16(tile[tx][ty + i * 8]);
  }
}

// all small weights, BOTH layers, one launch: grid (28,28,24), z = l*12 + idx
__global__ __launch_bounds__(256)
void convT_batch2(const float* Wr, const float* Wk, const float* Wv, const float* Wo,
                  const float* a1, const float* a2, const float* v1, const float* v2,
                  const float* g1, const float* g2, const float* w1, const float* w2,
                  __hip_bfloat16* WrT, __hip_bfloat16* WkT, __hip_bfloat16* WvT,
                  __hip_bfloat16* WoT, __hip_bfloat16* a1T, __hip_bfloat16* a2T,
                  __hip_bfloat16* v1T, __hip_bfloat16* v2T, __hip_bfloat16* g1T,
                  __hip_bfloat16* g2T, __hip_bfloat16* w1T, __hip_bfloat16* w2T)
{
  int l = blockIdx.z / 12, idx = blockIdx.z % 12;
  const size_t W2 = (size_t)CC * CC, WD = (size_t)DD * CC, WG = (size_t)192 * CC;
  const float* W; __hip_bfloat16* Wt; int K, N, KP, NP;
  switch (idx) {
    case 0:  W = Wr + l*W2;          Wt = WrT + l*W2; K = CC;  N = CC;  KP = CC;  NP = CC;  break;
    case 1:  W = Wk + l*W2;          Wt = WkT + l*W2; K = CC;  N = CC;  KP = CC;  NP = CC;  break;
    case 2:  W = Wv + l*W2;          Wt = WvT + l*W2; K = CC;  N = CC;  KP = CC;  NP = CC;  break;
    case 3:  W = Wo + l*W2;          Wt = WoT + l*W2; K = CC;  N = CC;  KP = CC;  NP = CC;  break;
    case 4:  W = a1 + l*WD;          Wt = a1T + l*WD; K = CC;  N = DD;  KP = CC;  NP = DD;  break;
    case 5:  W = a2 + l*WD;          Wt = a2T + l*WD; K = DD;  N = CC;  KP = DD;  NP = CC;  break;
    case 6:  W = v1 + l*WD;          Wt = v1T + l*WD; K = CC;  N = DD;  KP = CC;  NP = DD;  break;
    case 7:  W = v2 + l*WD;          Wt = v2T + l*WD; K = DD;  N = CC;  KP = DD;  NP = CC;  break;
    case 8:  W = g1 + l*(size_t)CC*DGG; Wt = g1T + l*WG; K = CC;  N = DGG; KP = CC;  NP = 192; break;
    case 9:  W = g2 + l*(size_t)CC*DGG; Wt = g2T + l*WG; K = DGG; N = CC;  KP = 192; NP = CC;  break;
    case 10: W = w1 + l*WD;          Wt = w1T + l*WD; K = CC;  N = DD;  KP = CC;  NP = DD;  break;
    default: W = w2 + l*WD;          Wt = w2T + l*WD; K = DD;  N = CC;  KP = DD;  NP = CC;  break;
  }
  if ((int)blockIdx.x * 32 >= NP || (int)blockIdx.y * 32 >= KP) return;
  convT_body(W, Wt, K, N, KP, NP, blockIdx.x, blockIdx.y);
}

// big channel-mix weights, both layers: grid (112, 28, 4), z = l*2 + which
__global__ __launch_bounds__(256)
void convT_big2(const float* fk, const float* fv,
                __hip_bfloat16* fkT, __hip_bfloat16* fvT)
{
  int l = blockIdx.z >> 1, which = blockIdx.z & 1;
  const size_t WF = (size_t)FF4 * CC;
  if (which == 0)
    convT_body(fk + l*WF, fkT + l*WF, CC, FF4, CC, FF4, blockIdx.x, blockIdx.y);
  else
    convT_body(fv + l*WF, fvT + l*WF, FF4, CC, FF4, CC, blockIdx.y, blockIdx.x);
}

// ---------------- bf16 MFMA GEMM body: C[M][N] = A[M][K] * Bt[N][K]^T ----------------
// 2-phase double-buffered K-loop: stage(t+1) issued before compute(t); one barrier
// per step. BN=128 for long-K GEMMs (reuse wins at nsteps>=14); BN=64 for
// short-K latency-bound GEMMs (block count wins at nsteps<=3).
// epi: 0 store f32, 1 add f32, 2 relu^2->bf16, 3 store bf16, 4 sigmoid->bf16 (0 past
// Nreal), 5 sigmoid(bias+v)->f32, 6 v-gate->f32, 7 decay(bias)->f32, 8 tanh->bf16,
// 9 store f32 + copy to auxw.
template<int BN>
__device__ __forceinline__ void gemm_body(const __hip_bfloat16* __restrict__ A,
    const __hip_bfloat16* __restrict__ Bt, float* __restrict__ C,
    __hip_bfloat16* __restrict__ Cbf, int N, int K, const float* __restrict__ bias,
    const float* __restrict__ aux0, const float* __restrict__ aux1,
    float* __restrict__ auxw, int Nreal, int bx, int by, int epi, ushort* ldsu)
{
  constexpr int WN = BN / 64;
  constexpr int WM = 4 / WN;
  constexpr int ROWS = 128 / WM;
  constexpr int MI = ROWS / 16;
  constexpr int BUF = (128 + BN) * 64;            // ushorts per buffer
  int tid = threadIdx.x;
  int lane = tid & 63, wave = tid >> 6;
  int wm, wn;
  if constexpr (WN == 2) { wm = wave >> 1; wn = wave & 1; } else { wm = wave; wn = 0; }
  int fl = lane & 15, fh = lane >> 4;
  int row0 = by * 128, col0 = bx * BN;

  const char* Abase = (const char*)A + (size_t)row0 * (size_t)(K * 2);
  const char* Bbase = (const char*)Bt + (size_t)col0 * (size_t)(K * 2);

  f32x4 acc[MI][4];
#pragma unroll
  for (int mi = 0; mi < MI; mi++)
#pragma unroll
    for (int ni = 0; ni < 4; ni++)
      acc[mi][ni] = (f32x4){0.f, 0.f, 0.f, 0.f};

  int srow = tid >> 3;
  int scol = (tid & 7) << 4;
  int ldsw = (wave << 10);

  auto stage = [&](int p, int k0) {
    char* AsB = (char*)(ldsu + p * BUF);
    char* BsB = AsB + 128 * 64 * 2;
#pragma unroll
    for (int it = 0; it < 4; ++it) {
      int r = it * 32 + srow;
      int cbs = scol ^ ((r & 7) << 4);
      size_t goff = (size_t)r * (size_t)(K * 2) + (size_t)(k0 * 2) + cbs;
      gload_lds16(Abase + goff, AsB + (it << 12) + ldsw);
      if constexpr (BN == 128) {
        gload_lds16(Bbase + goff, BsB + (it << 12) + ldsw);
      } else {
        if (it < 2) gload_lds16(Bbase + goff, BsB + (it << 12) + ldsw);
      }
    }
  };
  auto compute = [&](int p) {
    char* AsB = (char*)(ldsu + p * BUF);
    char* BsB = AsB + 128 * 64 * 2;
#pragma unroll
    for (int kk = 0; kk < 2; ++kk) {
      bf16x8 af[MI], bfr[4];
      int kb_ = kk * 64 + (fh << 4);
#pragma unroll
      for (int mi = 0; mi < MI; mi++) {
        int r = wm * ROWS + mi * 16 + fl;
        af[mi] = *(const bf16x8*)(AsB + r * 128 + (kb_ ^ ((r & 7) << 4)));
      }
#pragma unroll
      for (int ni = 0; ni < 4; ni++) {
        int r = wn * 64 + ni * 16 + fl;
        bfr[ni] = *(const bf16x8*)(BsB + r * 128 + (kb_ ^ ((r & 7) << 4)));
      }
#pragma unroll
      for (int mi = 0; mi < MI; mi++)
#pragma unroll
        for (int ni = 0; ni < 4; ni++)
          acc[mi][ni] = __builtin_amdgcn_mfma_f32_16x16x32_bf16(af[mi], bfr[ni], acc[mi][ni], 0, 0, 0);
    }
  };

  stage(0, 0);
  __syncthreads();
  int cur = 0;
  for (int k0 = 64; k0 < K; k0 += 64) {
    stage(cur ^ 1, k0);
    compute(cur);
    __syncthreads();
    cur ^= 1;
  }
  compute(cur);

  if (epi == 2 || epi == 3 || epi == 4 || epi == 8) {
    __syncthreads();
#pragma unroll
    for (int mi = 0; mi < MI; mi++) {
      int lrow0 = wm * ROWS + mi * 16 + fh * 4;
#pragma unroll
      for (int ni = 0; ni < 4; ni++) {
        int lcol = wn * 64 + ni * 16 + fl;
        int gcol = col0 + lcol;
#pragma unroll
        for (int e = 0; e < 4; e++) {
          float v = acc[mi][ni][e];
          float o;
          if (epi == 2)      { float t2 = fmaxf(v, 0.f); o = t2 * t2; }
          else if (epi == 4) { o = (gcol < Nreal) ? sigmoidf_(v) : 0.f; }
          else if (epi == 8) { o = tanhf(v); }
          else               { o = v; }
          ldsu[(lrow0 + e) * BN + lcol] = bf16bits(o);
        }
      }
    }
    __syncthreads();
    constexpr int ITER = (128 * BN) / (256 * 8);
#pragma unroll
    for (int it2 = 0; it2 < ITER; ++it2) {
      int idx = (it2 * 256 + tid) * 8;
      int row = idx / BN;
      int col = idx - row * BN;
      float4 v4 = *(const float4*)&ldsu[idx];
      *(float4*)((char*)Cbf + ((size_t)(row0 + row) * N + col0 + col) * 2) = v4;
    }
  } else {
#pragma unroll
    for (int mi = 0; mi < MI; mi++) {
      int crow0 = row0 + wm * ROWS + mi * 16 + fh * 4;
#pragma unroll
      for (int ni = 0; ni < 4; ni++) {
        int ccol = col0 + wn * 64 + ni * 16 + fl;
#pragma unroll
        for (int e = 0; e < 4; e++) {
          size_t off = (size_t)(crow0 + e) * N + ccol;
          float v = acc[mi][ni][e];
          switch (epi) {
            case 0: C[off] = v; break;
            case 1: C[off] += v; break;
            case 5: C[off] = sigmoidf_(bias[ccol] + v); break;
            case 6: { float sg = sigmoidf_(bias[ccol] + v);
                      float vv = aux0[off];
                      C[off] = vv + (aux1[off] - vv) * sg; } break;
            case 9: C[off] = v; auxw[off] = v; break;
            default: { float z_ = bias[ccol] + v;                       // 7: decay
                       float sp_ = fmaxf(-z_, 0.f) + log1pf(expf(-fabsf(z_)));
                       C[off] = expf(-expf(-sp_ - 0.5f)); } break;
          }
        }
      }
    }
  }
}

template<int BN>
__global__ __launch_bounds__(256)
void gemm_ep(const __hip_bfloat16* __restrict__ A, const __hip_bfloat16* __restrict__ Bt,
             float* __restrict__ C, __hip_bfloat16* __restrict__ Cbf,
             int N, int K, const float* __restrict__ bias,
             const float* __restrict__ aux0, const float* __restrict__ aux1,
             int Nreal, int epi)
{
  __shared__ __align__(16) ushort lds[2 * (128 + BN) * 64];
  gemm_body<BN>(A, Bt, C, Cbf, N, K, bias, aux0, aux1, nullptr, Nreal,
                blockIdx.x, blockIdx.y, epi, lds);
}

// merged r/k/v projections + LoRA stage-1, grid (7,16,4)
// z<3: rkv (BN=128). z==3: bx 0 w1(tanh), 1 a1, 2 v1, 3..5 g1, 6 idle.
__global__ __launch_bounds__(256)
void gemm_rkv_lora1(const __hip_bfloat16* Ar, const __hip_bfloat16* Ak, const __hip_bfloat16* Av,
                    const __hip_bfloat16* mixw, const __hip_bfloat16* mixa, const __hip_bfloat16* mixg,
                    const __hip_bfloat16* Br, const __hip_bfloat16* Bk, const __hip_bfloat16* Bv,
                    const __hip_bfloat16* w1T, const __hip_bfloat16* a1T,
                    const __hip_bfloat16* v1T, const __hip_bfloat16* g1T,
                    float* Cr, float* Ck, float* Cv, float* vfirst,
                    __hip_bfloat16* t64w, __hip_bfloat16* t64a,
                    __hip_bfloat16* t64v, __hip_bfloat16* t160, int copy_vfirst)
{
  __shared__ __align__(16) ushort lds[2 * (128 + 128) * 64];
  int z = blockIdx.z;
  if (z < 3) {
    const __hip_bfloat16 *A, *Bt; float* C; int epi = 0; float* aw = nullptr;
    if (z == 0)      { A = Ar; Bt = Br; C = Cr; }
    else if (z == 1) { A = Ak; Bt = Bk; C = Ck; }
    else             { A = Av; Bt = Bv; C = Cv;
                       if (copy_vfirst) { epi = 9; aw = vfirst; } }
    gemm_body<128>(A, Bt, C, nullptr, CC, CC, nullptr, nullptr, nullptr, aw, CC,
                   blockIdx.x, blockIdx.y, epi, lds);
  } else {
    int bx = blockIdx.x;
    if (bx >= 6) return;
    const __hip_bfloat16 *A, *Bt; __hip_bfloat16* Cbf; int N, epi, bxx, Nreal;
    if (bx == 0)      { A = mixw; Bt = w1T; Cbf = t64w; N = 64;  epi = 8; bxx = 0; Nreal = 64; }
    else if (bx == 1) { A = mixa; Bt = a1T; Cbf = t64a; N = 64;  epi = 3; bxx = 0; Nreal = 64; }
    else if (bx == 2) { A = Av;   Bt = v1T; Cbf = t64v; N = 64;  epi = 3; bxx = 0; Nreal = 64; }
    else              { A = mixg; Bt = g1T; Cbf = t160; N = 192; epi = 4; bxx = bx - 3; Nreal = DGG; }
    gemm_body<64>(A, Bt, nullptr, Cbf, N, CC, nullptr, nullptr, nullptr, nullptr, Nreal,
                  bxx, blockIdx.y, epi, lds);
  }
}

// batched LoRA stage-2: grid (14,16,nz), BN=64 (latency-bound K=64/192 ->
// maximize block count; 48KB LDS -> 3 blocks/CU).
// z: 0 w2(decay), 1 a2(sig), 2 g2, 3 v2(gate)
__global__ __launch_bounds__(256)
void lora2_batch(const __hip_bfloat16* t64w, const __hip_bfloat16* t64a,
                 const __hip_bfloat16* t160, const __hip_bfloat16* t64v,
                 const __hip_bfloat16* w2T, const __hip_bfloat16* a2T,
                 const __hip_bfloat16* g2T, const __hip_bfloat16* v2T,
                 float* dcy, float* ab, float* gb, float* vb,
                 const float* w0l, const float* a0l, const float* v0l,
                 const float* vfirst)
{
  __shared__ __align__(16) ushort lds[2 * (128 + 64) * 64];
  int z = blockIdx.z;
  const __hip_bfloat16 *A, *Bt; float* C; const float* bias;
  const float *ax0, *ax1; int K, epi;
  if (z == 0)      { A = t64w; Bt = w2T; C = dcy; bias = w0l; K = 64;  epi = 7; ax0 = nullptr; ax1 = nullptr; }
  else if (z == 1) { A = t64a; Bt = a2T; C = ab;  bias = a0l; K = 64;  epi = 5; ax0 = nullptr; ax1 = nullptr; }
  else if (z == 2) { A = t160; Bt = g2T; C = gb;  bias = nullptr; K = 192; epi = 0; ax0 = nullptr; ax1 = nullptr; }
  else             { A = t64v; Bt = v2T; C = vb;  bias = v0l; K = 64;  epi = 6; ax0 = vb; ax1 = vfirst; }
  gemm_body<64>(A, Bt, C, nullptr, CC, K, bias, ax0, ax1, nullptr, CC,
                blockIdx.x, blockIdx.y, epi, lds);
}

// ================= chunk-parallel RWKV7 scan =================
// Phase 1 (scanrs, 896 blocks): ROW-split — wave w owns rows w16..w16+15;
// lane = (row = w16 + (lane&15), col-quad = lane>>4). Reductions via 4-lane
// shfl_xor(16/32). Dual 8-deep LDS ring; ONE barrier + counted vmcnt per 8 steps.
// FUSED PREP: loads RAW streams (r, d, k_raw, a, v); each wave normalizes its
// own 2 slots in-place after its loads land (kk-norm -> ain/bin, k-gating),
// then the phase barrier publishes to all waves.
__global__ __launch_bounds__(256)
void scanrs_kernel(const float* __restrict__ rp, const float* __restrict__ dp,
                   const float* __restrict__ kp, const float* __restrict__ ap,
                   const float* __restrict__ vp,
                   const float* __restrict__ kkg, const float* __restrict__ kag,
                   float* __restrict__ yp, float* __restrict__ ubuf,
                   float* __restrict__ Pc, float* __restrict__ Zc)
{
  int bid = blockIdx.x;
  int bh = bid >> 4, c = bid & 15;        // NCH=16
  int b = bh / HH, h = bh - b * HH;
  int tid = threadIdx.x, lane = tid & 63, w = tid >> 6;
  int rl = lane & 15, quad = lane >> 4;
  int row = w * 16 + rl;
  int col0 = quad * 16;
  __shared__ __align__(16) float ring[2][8][6][64];  // 0 r,1 d,2 k,3 ain,4 bin,5 v

  float s[16], p[16];
#pragma unroll
  for (int jj = 0; jj < 16; jj++) {
    s[jj] = 0.f;
    p[jj] = (col0 + jj == row) ? 1.f : 0.f;
  }
  size_t cbase = ((size_t)b * TT + (size_t)c * CL) * CC + (size_t)h * NN;
  float kkc = kkg[h * NN + lane];
  float kac = kag[h * NN + lane];

  // wave w fills ring slots 2w, 2w+1 (5 raw streams each = 10 loads per phase)
  auto issueL = [&](int q) {
    int rr = q & 1;
#pragma unroll
    for (int k2 = 0; k2 < 2; ++k2) {
      int st = 2 * w + k2;
      size_t o = cbase + (size_t)(q * 8 + st) * CC + lane;
      gload_lds4(rp + o, &ring[rr][st][0][0]);
      gload_lds4(dp + o, &ring[rr][st][1][0]);
      gload_lds4(kp + o, &ring[rr][st][2][0]);
      gload_lds4(ap + o, &ring[rr][st][3][0]);
      gload_lds4(vp + o, &ring[rr][st][5][0]);
    }
  };

  issueL(0);
  for (int q = 0; q < CL / 8; ++q) {
    int rr = q & 1;
    // boundary: own loads for ring[rr] complete (stores issued after them may
    // remain outstanding: 16 y/u stores per phase -> vmcnt(16) for q>=1).
    if (q == 0) asm volatile("s_waitcnt vmcnt(0)" ::: "memory");
    else        asm volatile("s_waitcnt vmcnt(16)" ::: "memory");
    __builtin_amdgcn_sched_barrier(0);
    // fused prep on own slots (read raw k/a, write gated k / ain / bin)
#pragma unroll
    for (int k2 = 0; k2 < 2; ++k2) {
      int st = 2 * w + k2;
      float kraw = ring[rr][st][2][lane];
      float araw = ring[rr][st][3][lane];
      float kk = kraw * kkc;
      float ss = waveRedSum(kk * kk);
      float kkn = kk / fmaxf(sqrtf(ss), 1e-12f);
      ring[rr][st][2][lane] = kraw * (1.f + (araw - 1.f) * kac);
      ring[rr][st][3][lane] = -kkn;
      ring[rr][st][4][lane] = kkn * araw;
    }
    asm volatile("s_waitcnt lgkmcnt(0)" ::: "memory");
    __builtin_amdgcn_s_barrier();
    __builtin_amdgcn_sched_barrier(0);
    if (q + 1 < CL / 8) issueL(q + 1);   // ring[(q+1)&1]: consumed 2 phases ago
    __builtin_amdgcn_sched_barrier(0);   // pin loads before this phase's stores
#pragma unroll 2
    for (int st = 0; st < 8; ++st) {
      int t = q * 8 + st;
      float rv[16], dv[16], kv[16], av[16], bv[16];
#pragma unroll
      for (int qd = 0; qd < 4; qd++) {
        *(float4*)&rv[qd * 4] = *(const float4*)&ring[rr][st][0][col0 + qd * 4];
        *(float4*)&dv[qd * 4] = *(const float4*)&ring[rr][st][1][col0 + qd * 4];
        *(float4*)&kv[qd * 4] = *(const float4*)&ring[rr][st][2][col0 + qd * 4];
        *(float4*)&av[qd * 4] = *(const float4*)&ring[rr][st][3][col0 + qd * 4];
        *(float4*)&bv[qd * 4] = *(const float4*)&ring[rr][st][4][col0 + qd * 4];
      }
      float vi = ring[rr][st][5][row];
      float sa0 = 0.f, sa1 = 0.f, pa0 = 0.f, pa1 = 0.f;
#pragma unroll
      for (int jj = 0; jj < 8; jj++) {
        sa0 = fmaf(s[jj],     av[jj],     sa0);
        sa1 = fmaf(s[jj + 8], av[jj + 8], sa1);
        pa0 = fmaf(p[jj],     av[jj],     pa0);
        pa1 = fmaf(p[jj + 8], av[jj + 8], pa1);
      }
      float sa = sa0 + sa1;
      sa += __shfl_xor(sa, 16, 64); sa += __shfl_xor(sa, 32, 64);
      float pa = pa0 + pa1;
      pa += __shfl_xor(pa, 16, 64); pa += __shfl_xor(pa, 32, 64);
      float y0 = 0.f, y1 = 0.f, u0 = 0.f, u1 = 0.f;
#pragma unroll
      for (int jj = 0; jj < 8; jj++) {
        s[jj]     = fmaf(s[jj],     dv[jj],     fmaf(sa, bv[jj],     vi * kv[jj]));
        y0 = fmaf(s[jj], rv[jj], y0);
        p[jj]     = fmaf(p[jj],     dv[jj],     pa * bv[jj]);
        u0 = fmaf(p[jj], rv[jj], u0);
        s[jj + 8] = fmaf(s[jj + 8], dv[jj + 8], fmaf(sa, bv[jj + 8], vi * kv[jj + 8]));
        y1 = fmaf(s[jj + 8], rv[jj + 8], y1);
        p[jj + 8] = fmaf(p[jj + 8], dv[jj + 8], pa * bv[jj + 8]);
        u1 = fmaf(p[jj + 8], rv[jj + 8], u1);
      }
      float yv_ = y0 + y1;
      yv_ += __shfl_xor(yv_, 16, 64); yv_ += __shfl_xor(yv_, 32, 64);
      float uv_ = u0 + u1;
      uv_ += __shfl_xor(uv_, 16, 64); uv_ += __shfl_xor(uv_, 32, 64);
      if (quad == 0) {
        yp[cbase + (size_t)t * CC + row] = yv_;
        ubuf[((size_t)bid * CL + t) * 64 + row] = uv_;
      }
    }
  }

  float* zp = Zc + ((size_t)bid * 64 + row) * 64 + col0;
  float* pq = Pc + ((size_t)bid * 64 + row) * 64 + col0;
#pragma unroll
  for (int q4 = 0; q4 < 4; q4++) {
    *(float4*)&zp[q4 * 4] = make_float4(s[q4*4], s[q4*4+1], s[q4*4+2], s[q4*4+3]);
    *(float4*)&pq[q4 * 4] = make_float4(p[q4*4], p[q4*4+1], p[q4*4+2], p[q4*4+3]);
  }
}

// Phase 2 (56 blocks, 512 threads): Sin[c] = S; S = S*P_c + Z_c, sequential over c.
__global__ __launch_bounds__(512)
void scanp2_kernel(const float* __restrict__ Pc, const float* __restrict__ Zc,
                   float* __restrict__ Sin)
{
  int bh = blockIdx.x;
  int tid = threadIdx.x;
  int i = tid & 63, jg = tid >> 6, j0 = jg * 8;
  int sr = tid >> 3, sq = (tid & 7) * 8;
  __shared__ float S_lds[64][65];
  __shared__ __align__(16) float P_lds[64][68];

#pragma unroll
  for (int jj = 0; jj < 8; jj++) S_lds[i][j0 + jj] = 0.f;

  size_t b0 = (size_t)bh * NCH * 4096;
  float4 pr0 = *(const float4*)(Pc + b0 + (size_t)sr * 64 + sq);
  float4 pr1 = *(const float4*)(Pc + b0 + (size_t)sr * 64 + sq + 4);

  for (int c = 0; c < NCH; c++) {
    size_t bidc = (size_t)bh * NCH + c;
    *(float4*)&P_lds[sr][sq]     = pr0;
    *(float4*)&P_lds[sr][sq + 4] = pr1;
    if (c + 1 < NCH) {
      size_t bn = (bidc + 1) * 4096;
      pr0 = *(const float4*)(Pc + bn + (size_t)sr * 64 + sq);
      pr1 = *(const float4*)(Pc + bn + (size_t)sr * 64 + sq + 4);
    }
    float sv[8];
#pragma unroll
    for (int jj = 0; jj < 8; jj++) sv[jj] = S_lds[i][j0 + jj];
    {
      float4* sp_ = (float4*)(Sin + bidc * 4096 + (size_t)i * 64 + j0);
      sp_[0] = make_float4(sv[0], sv[1], sv[2], sv[3]);
      sp_[1] = make_float4(sv[4], sv[5], sv[6], sv[7]);
    }
    const float4* zp4 = (const float4*)(Zc + bidc * 4096 + (size_t)i * 64 + j0);
    float4 z0 = zp4[0], z1 = zp4[1];
    __syncthreads();
    float nv[8] = {0.f, 0.f, 0.f, 0.f, 0.f, 0.f, 0.f, 0.f};
    for (int m = 0; m < 64; m++) {
      float sm = S_lds[i][m];
#pragma unroll
      for (int jj = 0; jj < 8; jj++)
        nv[jj] = fmaf(sm, P_lds[m][j0 + jj], nv[jj]);
    }
    nv[0] += z0.x; nv[1] += z0.y; nv[2] += z0.z; nv[3] += z0.w;
    nv[4] += z1.x; nv[5] += z1.y; nv[6] += z1.z; nv[7] += z1.w;
    __syncthreads();
#pragma unroll
    for (int jj = 0; jj < 8; jj++) S_lds[i][j0 + jj] = nv[jj];
  }
}

// Phase 3 + groupnorm + rk*v + gate fused (896 blocks); k-gating applied inline
__global__ __launch_bounds__(256)
void scanp3gn_kernel(const float* __restrict__ Sin, const float* __restrict__ ubuf,
                     const float* __restrict__ y0p,
                     const float* __restrict__ rp, const float* __restrict__ kp,
                     const float* __restrict__ ap, const float* __restrict__ kag,
                     const float* __restrict__ vp, const float* __restrict__ gp,
                     const float* __restrict__ lnxw, const float* __restrict__ lnxb,
                     const float* __restrict__ rkco,
                     __hip_bfloat16* __restrict__ yout)
{
  int bid = blockIdx.x;
  int bh = bid >> 4, c = bid & 15;        // NCH=16
  int b = bh / HH, h = bh - b * HH;
  int tid = threadIdx.x, i = tid & 63, wv = tid >> 6;
  __shared__ float S_lds[64][65];
  __shared__ __align__(16) float U_lds[CL][64];
  {
    int r = tid >> 2, q = tid & 3;
    const float* src = Sin + (size_t)bid * 4096 + (size_t)r * 64 + q * 16;
#pragma unroll
    for (int jj = 0; jj < 16; jj++) S_lds[r][q * 16 + jj] = src[jj];
  }
  {
    int r = tid >> 3, q = tid & 7;
    const float4* us = (const float4*)(ubuf + (size_t)bid * (CL * 64) + (size_t)r * 64 + q * 8);
    float4* ud = (float4*)(&U_lds[r][q * 8]);
    ud[0] = us[0]; ud[1] = us[1];
  }
  __syncthreads();
  float sreg[64];
#pragma unroll
  for (int m = 0; m < 64; m++) sreg[m] = S_lds[i][m];
  int ch = h * NN + i;
  float lw = lnxw[ch], lb = lnxb[ch], rkc = rkco[ch], kaw = kag[ch];
  size_t rowbase = ((size_t)b * TT + (size_t)c * CL) * CC + ch;
#pragma unroll 1
  for (int tt = 0; tt < CL / 4; tt++) {
    int t = wv * (CL / 4) + tt;
    size_t off = rowbase + (size_t)t * CC;
    float a0 = 0.f, a1 = 0.f, a2 = 0.f, a3 = 0.f;
#pragma unroll
    for (int m4 = 0; m4 < 16; m4++) {
      float4 uu = *(const float4*)&U_lds[t][m4 * 4];
      a0 = fmaf(sreg[m4*4+0], uu.x, a0);
      a1 = fmaf(sreg[m4*4+1], uu.y, a1);
      a2 = fmaf(sreg[m4*4+2], uu.z, a2);
      a3 = fmaf(sreg[m4*4+3], uu.w, a3);
    }
    float yv = y0p[off] + (a0 + a1) + (a2 + a3);
    float s1 = waveRedSum(yv);
    float s2 = waveRedSum(yv * yv);
    float mean = s1 * (1.f / 64.f);
    float var  = s2 * (1.f / 64.f) - mean * mean;
    float norm = (yv - mean) * rsqrtf(var + 0.00064f);
    float rv = rp[off], kraw = kp[off], vv = vp[off], gv = gp[off];
    float aval = ap[off];
    float kg = kraw * (1.f + (aval - 1.f) * kaw);
    float rk = waveRedSum(rv * kg * rkc);
    yout[off] = __float2bfloat16((norm * lw + lb + rk * vv) * gv);
  }
}

// ---------------- host ----------------
extern "C" void kernel_launch(void* const* d_in, const int* in_sizes, int n_in,
                              void* d_out, int out_size, void* d_ws, size_t ws_size,
                              hipStream_t stream)
{
  const int*   idx    = (const int*)d_in[0];
  const float* emb    = (const float*)d_in[1];
  const float* ln0_w  = (const float*)d_in[2];
  const float* ln0_b  = (const float*)d_in[3];
  const float* ln1_w  = (const float*)d_in[4];
  const float* ln1_b  = (const float*)d_in[5];
  const float* ln2_w  = (const float*)d_in[6];
  const float* ln2_b  = (const float*)d_in[7];
  const float* x_r    = (const float*)d_in[8];
  const float* x_w    = (const float*)d_in[9];
  const float* x_k    = (const float*)d_in[10];
  const float* x_v    = (const float*)d_in[11];
  const float* x_a    = (const float*)d_in[12];
  const float* x_g    = (const float*)d_in[13];
  const float* w0     = (const float*)d_in[14];
  const float* w1     = (const float*)d_in[15];
  const float* w2     = (const float*)d_in[16];
  const float* a0     = (const float*)d_in[17];
  const float* a1     = (const float*)d_in[18];
  const float* a2     = (const float*)d_in[19];
  const float* v0     = (const float*)d_in[20];
  const float* v1     = (const float*)d_in[21];
  const float* v2     = (const float*)d_in[22];
  const float* g1     = (const float*)d_in[23];
  const float* g2     = (const float*)d_in[24];
  const float* k_k    = (const float*)d_in[25];
  const float* k_a    = (const float*)d_in[26];
  const float* r_k    = (const float*)d_in[27];
  const float* Wr     = (const float*)d_in[28];
  const float* Wk     = (const float*)d_in[29];
  const float* Wv     = (const float*)d_in[30];
  const float* Wo     = (const float*)d_in[31];
  const float* lnx_w  = (const float*)d_in[32];
  const float* lnx_b  = (const float*)d_in[33];
  const float* f_xk   = (const float*)d_in[34];
  const float* f_key  = (const float*)d_in[35];
  const float* f_val  = (const float*)d_in[36];
  const float* lnout_w = (const float*)d_in[37];
  const float* lnout_b = (const float*)d_in[38];
  const float* head_w  = (const float*)d_in[39];
  float* out = (float*)d_out;

  const size_t MC = (size_t)MM * CC;
  const size_t W2 = (size_t)CC * CC;
  const size_t WD = (size_t)DD * CC;
  const size_t WG = (size_t)192 * CC;
  const size_t WF = (size_t)FF4 * CC;
  float* ws   = (float*)d_ws;
  float* x      = ws;
  float* vfirst = x + MC;
  float* rb     = vfirst + MC;
  float* dcy    = rb + MC;       // rb+dcy contiguous: h_bf alias spans both
  float* kb     = dcy + MC;
  float* vb     = kb + MC;
  float* ab     = vb + MC;
  float* gb     = ab + MC;
  float* ainb   = gb + MC;       // unused (prep fused into scanrs)
  float* binb   = ainb + MC;     // unused
  float* yb     = binb + MC;
  float* ubuf   = yb + MC;       // 896*32*64 = MC
  float* Pcb    = ubuf + MC;     // 896*4096 = 2*MC
  float* Zcb    = Pcb + 2 * MC;
  float* Sinb   = Zcb + 2 * MC;
  float* fend   = Sinb + 2 * MC;
  (void)ainb; (void)binb;

  __hip_bfloat16* mixr_bf = (__hip_bfloat16*)fend;
  __hip_bfloat16* mixw_bf = mixr_bf + MC;
  __hip_bfloat16* mixk_bf = mixw_bf + MC;
  __hip_bfloat16* mixv_bf = mixk_bf + MC;
  __hip_bfloat16* mixa_bf = mixv_bf + MC;
  __hip_bfloat16* mixg_bf = mixa_bf + MC;
  // both-layer transposed weights
  __hip_bfloat16* WrT = mixg_bf + MC;        // 2*W2
  __hip_bfloat16* WkT = WrT + 2 * W2;
  __hip_bfloat16* WvT = WkT + 2 * W2;
  __hip_bfloat16* WoT = WvT + 2 * W2;
  __hip_bfloat16* fkT = WoT + 2 * W2;        // 2*WF
  __hip_bfloat16* fvT = fkT + 2 * WF;
  __hip_bfloat16* w1T = fvT + 2 * WF;        // 2*WD each
  __hip_bfloat16* a1T = w1T + 2 * WD;
  __hip_bfloat16* v1T = a1T + 2 * WD;
  __hip_bfloat16* w2T = v1T + 2 * WD;
  __hip_bfloat16* a2T = w2T + 2 * WD;
  __hip_bfloat16* v2T = a2T + 2 * WD;
  __hip_bfloat16* g1T = v2T + 2 * WD;        // 2*WG each
  __hip_bfloat16* g2T = g1T + 2 * WG;
  __hip_bfloat16* t64w = g2T + 2 * WG;       // [2048][64]
  __hip_bfloat16* t64a = t64w + (size_t)MM * 64;
  __hip_bfloat16* t64v = t64a + (size_t)MM * 64;
  __hip_bfloat16* t160 = t64v + (size_t)MM * 64;   // [2048][192]
  // aliases on dead f32 regions
  __hip_bfloat16* h_bf  = (__hip_bfloat16*)rb;     // [2048][3584] over rb+dcy
  __hip_bfloat16* yg_bf = (__hip_bfloat16*)ainb;   // [2048][896] (ainb now free)

  dim3 blk(256);

  // all weight transposes up front (both layers)
  convT_batch2<<<dim3(28, 28, 24), blk, 0, stream>>>(
      Wr, Wk, Wv, Wo, a1, a2, v1, v2, g1, g2, w1, w2,
      WrT, WkT, WvT, WoT, a1T, a2T, v1T, v2T, g1T, g2T, w1T, w2T);
  convT_big2<<<dim3(112, 28, 4), blk, 0, stream>>>(f_key, f_val, fkT, fvT);

  ln_kernel<<<MM, blk, 0, stream>>>(emb, idx, ln0_w, ln0_b, x);

  for (int l = 0; l < 2; l++) {
    lnmix6_kernel<<<MM, blk, 0, stream>>>(x, ln1_w + l * CC, ln1_b + l * CC,
        x_r + l * CC, x_w + l * CC, x_k + l * CC, x_v + l * CC, x_a + l * CC, x_g + l * CC,
        mixr_bf, mixw_bf, mixk_bf, mixv_bf, mixa_bf, mixg_bf);

    // r,k,v projections + LoRA stage-1, one launch (vfirst copy via epi in layer 0)
    gemm_rkv_lora1<<<dim3(7, 16, 4), blk, 0, stream>>>(
        mixr_bf, mixk_bf, mixv_bf, mixw_bf, mixa_bf, mixg_bf,
        WrT + l * W2, WkT + l * W2, WvT + l * W2,
        w1T + l * WD, a1T + l * WD, v1T + l * WD, g1T + l * WG,
        rb, kb, vb, vfirst, t64w, t64a, t64v, t160, l == 0 ? 1 : 0);

    // LoRA stage 2 (decay, sigmoid, g, v-gate) — BN=64, 224 blocks per slice
    lora2_batch<<<dim3(14, 16, l == 0 ? 3 : 4), blk, 0, stream>>>(
        t64w, t64a, t160, t64v,
        w2T + l * WD, a2T + l * WD, g2T + l * WG, v2T + l * WD,
        dcy, ab, gb, vb, w0 + l * CC, a0 + l * CC, v0 + l * CC, vfirst);

    // chunked scan with fused prep (+fused gn in phase 3)
    scanrs_kernel<<<BB * HH * NCH, blk, 0, stream>>>(rb, dcy, kb, ab, vb,
        k_k + l * CC, k_a + l * CC, yb, ubuf, Pcb, Zcb);
    scanp2_kernel<<<BB * HH, dim3(512), 0, stream>>>(Pcb, Zcb, Sinb);
    scanp3gn_kernel<<<BB * HH * NCH, blk, 0, stream>>>(Sinb, ubuf, yb, rb, kb,
        ab, k_a + l * CC, vb, gb,
        lnx_w + l * CC, lnx_b + l * CC, r_k + (size_t)l * CC, yg_bf);

    // x += (y*g) @ Wo   (BN=64 -> 224 blocks)
    gemm_ep<64><<<dim3(14, 16), blk, 0, stream>>>(yg_bf, WoT + l * W2, x, nullptr, CC, CC,
                                                  nullptr, nullptr, nullptr, CC, 1);

    // ---- channel mix ----
    lnmixc_kernel<<<MM, blk, 0, stream>>>(x, ln2_w + l * CC, ln2_b + l * CC,
                                          f_xk + l * CC, mixr_bf);
    gemm_ep<128><<<dim3(28, 16), blk, 0, stream>>>(mixr_bf, fkT + l * WF, nullptr, h_bf,
                                                   FF4, CC, nullptr, nullptr, nullptr, FF4, 2);
    gemm_ep<64><<<dim3(14, 16), blk, 0, stream>>>(h_bf, fvT + l * WF, x, nullptr, CC, FF4,
                                                  nullptr, nullptr, nullptr, CC, 1);
  }

  head_kernel<<<MM, blk, 0, stream>>>(x, lnout_w, lnout_b, head_w, out);
}

// Round 22
// 650.602 us; speedup vs baseline: 1.0023x; 1.0023x over previous
//
#include <hip/hip_runtime.h>
#include <hip/hip_bf16.h>
#include <math.h>

#define CC 896
#define TT 512
#define BB 4
#define HH 14
#define NN 64
#define DD 64
#define DGG 160
#define FF4 3584
#define MM (BB*TT)   // 2048
#define NCH 16       // chunks per (b,h)
#define CL 32        // chunk length = TT/NCH

typedef __attribute__((ext_vector_type(8))) short bf16x8;
typedef __attribute__((ext_vector_type(4))) float f32x4;

__device__ __forceinline__ float waveRedSum(float x) {
#pragma unroll
  for (int off = 32; off > 0; off >>= 1) x += __shfl_xor(x, off, 64);
  return x;
}

__device__ __forceinline__ float sigmoidf_(float x) { return 1.f / (1.f + expf(-x)); }

__device__ __forceinline__ ushort bf16bits(float v) {
  __hip_bfloat16 h = __float2bfloat16(v);
  return *(ushort*)&h;
}

__device__ __forceinline__ void gload_lds16(const void* g, void* l) {
  __builtin_amdgcn_global_load_lds((const __attribute__((address_space(1))) void*)g,
                                   (__attribute__((address_space(3))) void*)l, 16, 0, 0);
}
__device__ __forceinline__ void gload_lds4(const void* g, void* l) {
  __builtin_amdgcn_global_load_lds((const __attribute__((address_space(1))) void*)g,
                                   (__attribute__((address_space(3))) void*)l, 4, 0, 0);
}

// ---------------- LayerNorm with idx gather (embedding + ln0) ----------------
__global__ __launch_bounds__(256)
void ln_kernel(const float* __restrict__ in, const int* __restrict__ idx,
               const float* __restrict__ w, const float* __restrict__ bvec,
               float* __restrict__ out)
{
  int m = blockIdx.x;
  const float* row = idx ? (in + (size_t)idx[m] * CC) : (in + (size_t)m * CC);
  float s = 0.f, s2 = 0.f;
  for (int c = threadIdx.x; c < CC; c += 256) { float x = row[c]; s += x; s2 += x * x; }
  __shared__ float red[2][4];
  float a = waveRedSum(s), b2 = waveRedSum(s2);
  int wid = threadIdx.x >> 6;
  if ((threadIdx.x & 63) == 0) { red[0][wid] = a; red[1][wid] = b2; }
  __syncthreads();
  s  = red[0][0] + red[0][1] + red[0][2] + red[0][3];
  s2 = red[1][0] + red[1][1] + red[1][2] + red[1][3];
  float mean = s * (1.f / CC);
  float var  = s2 * (1.f / CC) - mean * mean;
  float inv  = rsqrtf(var + 1e-5f);
  float* orow = out + (size_t)m * CC;
  for (int c = threadIdx.x; c < CC; c += 256)
    orow[c] = (row[c] - mean) * inv * w[c] + bvec[c];
}

// ---------------- final LN + head ----------------
__global__ __launch_bounds__(256)
void head_kernel(const float* __restrict__ x, const float* __restrict__ w,
                 const float* __restrict__ bvec, const float* __restrict__ hw,
                 float* __restrict__ out)
{
  int m = blockIdx.x;
  const float* row = x + (size_t)m * CC;
  float s = 0.f, s2 = 0.f;
  for (int c = threadIdx.x; c < CC; c += 256) { float v = row[c]; s += v; s2 += v * v; }
  __shared__ float red[2][4];
  float a = waveRedSum(s), b2 = waveRedSum(s2);
  int wid = threadIdx.x >> 6;
  if ((threadIdx.x & 63) == 0) { red[0][wid] = a; red[1][wid] = b2; }
  __syncthreads();
  s  = red[0][0] + red[0][1] + red[0][2] + red[0][3];
  s2 = red[1][0] + red[1][1] + red[1][2] + red[1][3];
  float mean = s * (1.f / CC);
  float var  = s2 * (1.f / CC) - mean * mean;
  float inv  = rsqrtf(var + 1e-5f);
  float p = 0.f;
  for (int c = threadIdx.x; c < CC; c += 256)
    p += ((row[c] - mean) * inv * w[c] + bvec[c]) * hw[c];
  p = waveRedSum(p);
  __shared__ float red2[4];
  if ((threadIdx.x & 63) == 0) red2[wid] = p;
  __syncthreads();
  if (threadIdx.x == 0) out[m] = red2[0] + red2[1] + red2[2] + red2[3];
}

// ---------------- fused LN + 6-way token-shift mix (time-mix entry) ----------------
__global__ __launch_bounds__(256)
void lnmix6_kernel(const float* __restrict__ x, const float* __restrict__ w,
                   const float* __restrict__ bvec,
                   const float* __restrict__ cr, const float* __restrict__ cw,
                   const float* __restrict__ ck, const float* __restrict__ cv,
                   const float* __restrict__ ca, const float* __restrict__ cg,
                   __hip_bfloat16* __restrict__ outr, __hip_bfloat16* __restrict__ outw,
                   __hip_bfloat16* __restrict__ outk, __hip_bfloat16* __restrict__ outv,
                   __hip_bfloat16* __restrict__ outa, __hip_bfloat16* __restrict__ outg)
{
  int m = blockIdx.x;
  int t = m % TT;
  const float* row  = x + (size_t)m * CC;
  const float* prow = row - CC;
  float s = 0.f, s2 = 0.f, sp = 0.f, sp2 = 0.f;
  for (int c = threadIdx.x; c < CC; c += 256) {
    float xv = row[c]; s += xv; s2 += xv * xv;
    if (t > 0) { float pv = prow[c]; sp += pv; sp2 += pv * pv; }
  }
  float a0 = waveRedSum(s), a1 = waveRedSum(s2), a2 = waveRedSum(sp), a3 = waveRedSum(sp2);
  __shared__ float red[4][4];
  int wid = threadIdx.x >> 6;
  if ((threadIdx.x & 63) == 0) { red[0][wid]=a0; red[1][wid]=a1; red[2][wid]=a2; red[3][wid]=a3; }
  __syncthreads();
  s   = red[0][0]+red[0][1]+red[0][2]+red[0][3];
  s2  = red[1][0]+red[1][1]+red[1][2]+red[1][3];
  sp  = red[2][0]+red[2][1]+red[2][2]+red[2][3];
  sp2 = red[3][0]+red[3][1]+red[3][2]+red[3][3];
  float mean = s * (1.f / CC);
  float inv  = rsqrtf(s2 * (1.f / CC) - mean * mean + 1e-5f);
  float meanp = sp * (1.f / CC);
  float invp  = rsqrtf(sp2 * (1.f / CC) - meanp * meanp + 1e-5f);
  for (int c = threadIdx.x; c < CC; c += 256) {
    float xnv = (row[c] - mean) * inv * w[c] + bvec[c];
    float xpv = (t > 0) ? (prow[c] - meanp) * invp * w[c] + bvec[c] : 0.f;
    float d = xpv - xnv;
    size_t off = (size_t)m * CC + c;
    outr[off] = __float2bfloat16(fmaf(d, cr[c], xnv));
    outw[off] = __float2bfloat16(fmaf(d, cw[c], xnv));
    outk[off] = __float2bfloat16(fmaf(d, ck[c], xnv));
    outv[off] = __float2bfloat16(fmaf(d, cv[c], xnv));
    outa[off] = __float2bfloat16(fmaf(d, ca[c], xnv));
    outg[off] = __float2bfloat16(fmaf(d, cg[c], xnv));
  }
}

// ---------------- fused LN + single mix (channel-mix entry) ----------------
__global__ __launch_bounds__(256)
void lnmixc_kernel(const float* __restrict__ x, const float* __restrict__ w,
                   const float* __restrict__ bvec, const float* __restrict__ coef,
                   __hip_bfloat16* __restrict__ outb)
{
  int m = blockIdx.x;
  int t = m % TT;
  const float* row  = x + (size_t)m * CC;
  const float* prow = row - CC;
  float s = 0.f, s2 = 0.f, sp = 0.f, sp2 = 0.f;
  for (int c = threadIdx.x; c < CC; c += 256) {
    float xv = row[c]; s += xv; s2 += xv * xv;
    if (t > 0) { float pv = prow[c]; sp += pv; sp2 += pv * pv; }
  }
  float a0 = waveRedSum(s), a1 = waveRedSum(s2), a2 = waveRedSum(sp), a3 = waveRedSum(sp2);
  __shared__ float red[4][4];
  int wid = threadIdx.x >> 6;
  if ((threadIdx.x & 63) == 0) { red[0][wid]=a0; red[1][wid]=a1; red[2][wid]=a2; red[3][wid]=a3; }
  __syncthreads();
  s   = red[0][0]+red[0][1]+red[0][2]+red[0][3];
  s2  = red[1][0]+red[1][1]+red[1][2]+red[1][3];
  sp  = red[2][0]+red[2][1]+red[2][2]+red[2][3];
  sp2 = red[3][0]+red[3][1]+red[3][2]+red[3][3];
  float mean = s * (1.f / CC);
  float inv  = rsqrtf(s2 * (1.f / CC) - mean * mean + 1e-5f);
  float meanp = sp * (1.f / CC);
  float invp  = rsqrtf(sp2 * (1.f / CC) - meanp * meanp + 1e-5f);
  for (int c = threadIdx.x; c < CC; c += 256) {
    float xnv = (row[c] - mean) * inv * w[c] + bvec[c];
    float xpv = (t > 0) ? (prow[c] - meanp) * invp * w[c] + bvec[c] : 0.f;
    outb[(size_t)m * CC + c] = __float2bfloat16(fmaf(xpv - xnv, coef[c], xnv));
  }
}

// ---------------- convert + transpose body ----------------
__device__ __forceinline__ void convT_body(const float* __restrict__ W,
                                           __hip_bfloat16* __restrict__ Wt,
                                           int K, int N, int KP, int NP,
                                           int bx, int by)
{
  __shared__ float tile[32][33];
  int bn = bx * 32, bk = by * 32;
  int tx = threadIdx.x & 31, ty = threadIdx.x >> 5;
#pragma unroll
  for (int i = 0; i < 4; i++) {
    int k = bk + ty + i * 8, n = bn + tx;
    tile[ty + i * 8][tx] = (k < K && n < N) ? W[(size_t)k * N + n] : 0.f;
  }
  __syncthreads();
#pragma unroll
  for (int i = 0; i < 4; i++) {
    int n = bn + ty + i * 8, k = bk + tx;
    if (n < NP && k < KP)
      Wt[(size_t)n * KP + k] = __float2bfloat16(tile[tx][ty + i * 8]);
  }
}

// all small weights, BOTH layers, one launch: grid (28,28,24), z = l*12 + idx
__global__ __launch_bounds__(256)
void convT_batch2(const float* Wr, const float* Wk, const float* Wv, const float* Wo,
                  const float* a1, const float* a2, const float* v1, const float* v2,
                  const float* g1, const float* g2, const float* w1, const float* w2,
                  __hip_bfloat16* WrT, __hip_bfloat16* WkT, __hip_bfloat16* WvT,
                  __hip_bfloat16* WoT, __hip_bfloat16* a1T, __hip_bfloat16* a2T,
                  __hip_bfloat16* v1T, __hip_bfloat16* v2T, __hip_bfloat16* g1T,
                  __hip_bfloat16* g2T, __hip_bfloat16* w1T, __hip_bfloat16* w2T)
{
  int l = blockIdx.z / 12, idx = blockIdx.z % 12;
  const size_t W2 = (size_t)CC * CC, WD = (size_t)DD * CC, WG = (size_t)192 * CC;
  const float* W; __hip_bfloat16* Wt; int K, N, KP, NP;
  switch (idx) {
    case 0:  W = Wr + l*W2;          Wt = WrT + l*W2; K = CC;  N = CC;  KP = CC;  NP = CC;  break;
    case 1:  W = Wk + l*W2;          Wt = WkT + l*W2; K = CC;  N = CC;  KP = CC;  NP = CC;  break;
    case 2:  W = Wv + l*W2;          Wt = WvT + l*W2; K = CC;  N = CC;  KP = CC;  NP = CC;  break;
    case 3:  W = Wo + l*W2;          Wt = WoT + l*W2; K = CC;  N = CC;  KP = CC;  NP = CC;  break;
    case 4:  W = a1 + l*WD;          Wt = a1T + l*WD; K = CC;  N = DD;  KP = CC;  NP = DD;  break;
    case 5:  W = a2 + l*WD;          Wt = a2T + l*WD; K = DD;  N = CC;  KP = DD;  NP = CC;  break;
    case 6:  W = v1 + l*WD;          Wt = v1T + l*WD; K = CC;  N = DD;  KP = CC;  NP = DD;  break;
    case 7:  W = v2 + l*WD;          Wt = v2T + l*WD; K = DD;  N = CC;  KP = DD;  NP = CC;  break;
    case 8:  W = g1 + l*(size_t)CC*DGG; Wt = g1T + l*WG; K = CC;  N = DGG; KP = CC;  NP = 192; break;
    case 9:  W = g2 + l*(size_t)CC*DGG; Wt = g2T + l*WG; K = DGG; N = CC;  KP = 192; NP = CC;  break;
    case 10: W = w1 + l*WD;          Wt = w1T + l*WD; K = CC;  N = DD;  KP = CC;  NP = DD;  break;
    default: W = w2 + l*WD;          Wt = w2T + l*WD; K = DD;  N = CC;  KP = DD;  NP = CC;  break;
  }
  if ((int)blockIdx.x * 32 >= NP || (int)blockIdx.y * 32 >= KP) return;
  convT_body(W, Wt, K, N, KP, NP, blockIdx.x, blockIdx.y);
}

// big channel-mix weights, both layers: grid (112, 28, 4), z = l*2 + which
__global__ __launch_bounds__(256)
void convT_big2(const float* fk, const float* fv,
                __hip_bfloat16* fkT, __hip_bfloat16* fvT)
{
  int l = blockIdx.z >> 1, which = blockIdx.z & 1;
  const size_t WF = (size_t)FF4 * CC;
  if (which == 0)
    convT_body(fk + l*WF, fkT + l*WF, CC, FF4, CC, FF4, blockIdx.x, blockIdx.y);
  else
    convT_body(fv + l*WF, fvT + l*WF, FF4, CC, FF4, CC, blockIdx.y, blockIdx.x);
}

// ---------------- bf16 MFMA GEMM body: C[M][N] = A[M][K] * Bt[N][K]^T ----------------
// 2-phase double-buffered K-loop: stage(t+1) issued before compute(t); one barrier
// per step. BN=128 for long-K GEMMs (reuse wins at nsteps>=14); BN=64 for
// short-K latency-bound GEMMs (block count wins at nsteps<=3).
// epi: 0 store f32, 1 add f32, 2 relu^2->bf16, 3 store bf16, 4 sigmoid->bf16 (0 past
// Nreal), 5 sigmoid(bias+v)->f32, 6 v-gate->f32, 7 decay(bias)->f32, 8 tanh->bf16,
// 9 store f32 + copy to auxw.
template<int BN>
__device__ __forceinline__ void gemm_body(const __hip_bfloat16* __restrict__ A,
    const __hip_bfloat16* __restrict__ Bt, float* __restrict__ C,
    __hip_bfloat16* __restrict__ Cbf, int N, int K, const float* __restrict__ bias,
    const float* __restrict__ aux0, const float* __restrict__ aux1,
    float* __restrict__ auxw, int Nreal, int bx, int by, int epi, ushort* ldsu)
{
  constexpr int WN = BN / 64;
  constexpr int WM = 4 / WN;
  constexpr int ROWS = 128 / WM;
  constexpr int MI = ROWS / 16;
  constexpr int BUF = (128 + BN) * 64;            // ushorts per buffer
  int tid = threadIdx.x;
  int lane = tid & 63, wave = tid >> 6;
  int wm, wn;
  if constexpr (WN == 2) { wm = wave >> 1; wn = wave & 1; } else { wm = wave; wn = 0; }
  int fl = lane & 15, fh = lane >> 4;
  int row0 = by * 128, col0 = bx * BN;

  const char* Abase = (const char*)A + (size_t)row0 * (size_t)(K * 2);
  const char* Bbase = (const char*)Bt + (size_t)col0 * (size_t)(K * 2);

  f32x4 acc[MI][4];
#pragma unroll
  for (int mi = 0; mi < MI; mi++)
#pragma unroll
    for (int ni = 0; ni < 4; ni++)
      acc[mi][ni] = (f32x4){0.f, 0.f, 0.f, 0.f};

  int srow = tid >> 3;
  int scol = (tid & 7) << 4;
  int ldsw = (wave << 10);

  auto stage = [&](int p, int k0) {
    char* AsB = (char*)(ldsu + p * BUF);
    char* BsB = AsB + 128 * 64 * 2;
#pragma unroll
    for (int it = 0; it < 4; ++it) {
      int r = it * 32 + srow;
      int cbs = scol ^ ((r & 7) << 4);
      size_t goff = (size_t)r * (size_t)(K * 2) + (size_t)(k0 * 2) + cbs;
      gload_lds16(Abase + goff, AsB + (it << 12) + ldsw);
      if constexpr (BN == 128) {
        gload_lds16(Bbase + goff, BsB + (it << 12) + ldsw);
      } else {
        if (it < 2) gload_lds16(Bbase + goff, BsB + (it << 12) + ldsw);
      }
    }
  };
  auto compute = [&](int p) {
    char* AsB = (char*)(ldsu + p * BUF);
    char* BsB = AsB + 128 * 64 * 2;
#pragma unroll
    for (int kk = 0; kk < 2; ++kk) {
      bf16x8 af[MI], bfr[4];
      int kb_ = kk * 64 + (fh << 4);
#pragma unroll
      for (int mi = 0; mi < MI; mi++) {
        int r = wm * ROWS + mi * 16 + fl;
        af[mi] = *(const bf16x8*)(AsB + r * 128 + (kb_ ^ ((r & 7) << 4)));
      }
#pragma unroll
      for (int ni = 0; ni < 4; ni++) {
        int r = wn * 64 + ni * 16 + fl;
        bfr[ni] = *(const bf16x8*)(BsB + r * 128 + (kb_ ^ ((r & 7) << 4)));
      }
#pragma unroll
      for (int mi = 0; mi < MI; mi++)
#pragma unroll
        for (int ni = 0; ni < 4; ni++)
          acc[mi][ni] = __builtin_amdgcn_mfma_f32_16x16x32_bf16(af[mi], bfr[ni], acc[mi][ni], 0, 0, 0);
    }
  };

  stage(0, 0);
  __syncthreads();
  int cur = 0;
  for (int k0 = 64; k0 < K; k0 += 64) {
    stage(cur ^ 1, k0);
    compute(cur);
    __syncthreads();
    cur ^= 1;
  }
  compute(cur);

  if (epi == 2 || epi == 3 || epi == 4 || epi == 8) {
    __syncthreads();
#pragma unroll
    for (int mi = 0; mi < MI; mi++) {
      int lrow0 = wm * ROWS + mi * 16 + fh * 4;
#pragma unroll
      for (int ni = 0; ni < 4; ni++) {
        int lcol = wn * 64 + ni * 16 + fl;
        int gcol = col0 + lcol;
#pragma unroll
        for (int e = 0; e < 4; e++) {
          float v = acc[mi][ni][e];
          float o;
          if (epi == 2)      { float t2 = fmaxf(v, 0.f); o = t2 * t2; }
          else if (epi == 4) { o = (gcol < Nreal) ? sigmoidf_(v) : 0.f; }
          else if (epi == 8) { o = tanhf(v); }
          else               { o = v; }
          ldsu[(lrow0 + e) * BN + lcol] = bf16bits(o);
        }
      }
    }
    __syncthreads();
    constexpr int ITER = (128 * BN) / (256 * 8);
#pragma unroll
    for (int it2 = 0; it2 < ITER; ++it2) {
      int idx = (it2 * 256 + tid) * 8;
      int row = idx / BN;
      int col = idx - row * BN;
      float4 v4 = *(const float4*)&ldsu[idx];
      *(float4*)((char*)Cbf + ((size_t)(row0 + row) * N + col0 + col) * 2) = v4;
    }
  } else {
#pragma unroll
    for (int mi = 0; mi < MI; mi++) {
      int crow0 = row0 + wm * ROWS + mi * 16 + fh * 4;
#pragma unroll
      for (int ni = 0; ni < 4; ni++) {
        int ccol = col0 + wn * 64 + ni * 16 + fl;
#pragma unroll
        for (int e = 0; e < 4; e++) {
          size_t off = (size_t)(crow0 + e) * N + ccol;
          float v = acc[mi][ni][e];
          switch (epi) {
            case 0: C[off] = v; break;
            case 1: C[off] += v; break;
            case 5: C[off] = sigmoidf_(bias[ccol] + v); break;
            case 6: { float sg = sigmoidf_(bias[ccol] + v);
                      float vv = aux0[off];
                      C[off] = vv + (aux1[off] - vv) * sg; } break;
            case 9: C[off] = v; auxw[off] = v; break;
            default: { float z_ = bias[ccol] + v;                       // 7: decay
                       float sp_ = fmaxf(-z_, 0.f) + log1pf(expf(-fabsf(z_)));
                       C[off] = expf(-expf(-sp_ - 0.5f)); } break;
          }
        }
      }
    }
  }
}

template<int BN>
__global__ __launch_bounds__(256)
void gemm_ep(const __hip_bfloat16* __restrict__ A, const __hip_bfloat16* __restrict__ Bt,
             float* __restrict__ C, __hip_bfloat16* __restrict__ Cbf,
             int N, int K, const float* __restrict__ bias,
             const float* __restrict__ aux0, const float* __restrict__ aux1,
             int Nreal, int epi)
{
  __shared__ __align__(16) ushort lds[2 * (128 + BN) * 64];
  gemm_body<BN>(A, Bt, C, Cbf, N, K, bias, aux0, aux1, nullptr, Nreal,
                blockIdx.x, blockIdx.y, epi, lds);
}

// merged r/k/v projections + LoRA stage-1, grid (7,16,4)
// z<3: rkv (BN=128). z==3: bx 0 w1(tanh), 1 a1, 2 v1, 3..5 g1, 6 idle.
__global__ __launch_bounds__(256)
void gemm_rkv_lora1(const __hip_bfloat16* Ar, const __hip_bfloat16* Ak, const __hip_bfloat16* Av,
                    const __hip_bfloat16* mixw, const __hip_bfloat16* mixa, const __hip_bfloat16* mixg,
                    const __hip_bfloat16* Br, const __hip_bfloat16* Bk, const __hip_bfloat16* Bv,
                    const __hip_bfloat16* w1T, const __hip_bfloat16* a1T,
                    const __hip_bfloat16* v1T, const __hip_bfloat16* g1T,
                    float* Cr, float* Ck, float* Cv, float* vfirst,
                    __hip_bfloat16* t64w, __hip_bfloat16* t64a,
                    __hip_bfloat16* t64v, __hip_bfloat16* t160, int copy_vfirst)
{
  __shared__ __align__(16) ushort lds[2 * (128 + 128) * 64];
  int z = blockIdx.z;
  if (z < 3) {
    const __hip_bfloat16 *A, *Bt; float* C; int epi = 0; float* aw = nullptr;
    if (z == 0)      { A = Ar; Bt = Br; C = Cr; }
    else if (z == 1) { A = Ak; Bt = Bk; C = Ck; }
    else             { A = Av; Bt = Bv; C = Cv;
                       if (copy_vfirst) { epi = 9; aw = vfirst; } }
    gemm_body<128>(A, Bt, C, nullptr, CC, CC, nullptr, nullptr, nullptr, aw, CC,
                   blockIdx.x, blockIdx.y, epi, lds);
  } else {
    int bx = blockIdx.x;
    if (bx >= 6) return;
    const __hip_bfloat16 *A, *Bt; __hip_bfloat16* Cbf; int N, epi, bxx, Nreal;
    if (bx == 0)      { A = mixw; Bt = w1T; Cbf = t64w; N = 64;  epi = 8; bxx = 0; Nreal = 64; }
    else if (bx == 1) { A = mixa; Bt = a1T; Cbf = t64a; N = 64;  epi = 3; bxx = 0; Nreal = 64; }
    else if (bx == 2) { A = Av;   Bt = v1T; Cbf = t64v; N = 64;  epi = 3; bxx = 0; Nreal = 64; }
    else              { A = mixg; Bt = g1T; Cbf = t160; N = 192; epi = 4; bxx = bx - 3; Nreal = DGG; }
    gemm_body<64>(A, Bt, nullptr, Cbf, N, CC, nullptr, nullptr, nullptr, nullptr, Nreal,
                  bxx, blockIdx.y, epi, lds);
  }
}

// batched LoRA stage-2: grid (14,16,nz), BN=64 (latency-bound K=64/192 ->
// maximize block count; 48KB LDS -> 3 blocks/CU).
// z: 0 w2(decay), 1 a2(sig), 2 g2, 3 v2(gate)
__global__ __launch_bounds__(256)
void lora2_batch(const __hip_bfloat16* t64w, const __hip_bfloat16* t64a,
                 const __hip_bfloat16* t160, const __hip_bfloat16* t64v,
                 const __hip_bfloat16* w2T, const __hip_bfloat16* a2T,
                 const __hip_bfloat16* g2T, const __hip_bfloat16* v2T,
                 float* dcy, float* ab, float* gb, float* vb,
                 const float* w0l, const float* a0l, const float* v0l,
                 const float* vfirst)
{
  __shared__ __align__(16) ushort lds[2 * (128 + 64) * 64];
  int z = blockIdx.z;
  const __hip_bfloat16 *A, *Bt; float* C; const float* bias;
  const float *ax0, *ax1; int K, epi;
  if (z == 0)      { A = t64w; Bt = w2T; C = dcy; bias = w0l; K = 64;  epi = 7; ax0 = nullptr; ax1 = nullptr; }
  else if (z == 1) { A = t64a; Bt = a2T; C = ab;  bias = a0l; K = 64;  epi = 5; ax0 = nullptr; ax1 = nullptr; }
  else if (z == 2) { A = t160; Bt = g2T; C = gb;  bias = nullptr; K = 192; epi = 0; ax0 = nullptr; ax1 = nullptr; }
  else             { A = t64v; Bt = v2T; C = vb;  bias = v0l; K = 64;  epi = 6; ax0 = vb; ax1 = vfirst; }
  gemm_body<64>(A, Bt, C, nullptr, CC, K, bias, ax0, ax1, nullptr, CC,
                blockIdx.x, blockIdx.y, epi, lds);
}

// ================= chunk-parallel RWKV7 scan =================
// Phase 1 (scanrs, 896 blocks): ROW-split — wave w owns rows w16..w16+15;
// lane = (row = w16 + (lane&15), col-quad = lane>>4). Reductions via 4-lane
// shfl_xor(16/32). Dual 8-deep LDS ring; ONE barrier + counted vmcnt per 8 steps.
// FUSED PREP: loads RAW streams (r, d, k_raw, a, v); each wave normalizes its
// own 2 slots in-place after its loads land (kk-norm -> ain/bin, k-gating),
// then the phase barrier publishes to all waves.
__global__ __launch_bounds__(256)
void scanrs_kernel(const float* __restrict__ rp, const float* __restrict__ dp,
                   const float* __restrict__ kp, const float* __restrict__ ap,
                   const float* __restrict__ vp,
                   const float* __restrict__ kkg, const float* __restrict__ kag,
                   float* __restrict__ yp, float* __restrict__ ubuf,
                   float* __restrict__ Pc, float* __restrict__ Zc)
{
  int bid = blockIdx.x;
  int bh = bid >> 4, c = bid & 15;        // NCH=16
  int b = bh / HH, h = bh - b * HH;
  int tid = threadIdx.x, lane = tid & 63, w = tid >> 6;
  int rl = lane & 15, quad = lane >> 4;
  int row = w * 16 + rl;
  int col0 = quad * 16;
  __shared__ __align__(16) float ring[2][8][6][64];  // 0 r,1 d,2 k,3 ain,4 bin,5 v

  float s[16], p[16];
#pragma unroll
  for (int jj = 0; jj < 16; jj++) {
    s[jj] = 0.f;
    p[jj] = (col0 + jj == row) ? 1.f : 0.f;
  }
  size_t cbase = ((size_t)b * TT + (size_t)c * CL) * CC + (size_t)h * NN;
  float kkc = kkg[h * NN + lane];
  float kac = kag[h * NN + lane];

  // wave w fills ring slots 2w, 2w+1 (5 raw streams each = 10 loads per phase)
  auto issueL = [&](int q) {
    int rr = q & 1;
#pragma unroll
    for (int k2 = 0; k2 < 2; ++k2) {
      int st = 2 * w + k2;
      size_t o = cbase + (size_t)(q * 8 + st) * CC + lane;
      gload_lds4(rp + o, &ring[rr][st][0][0]);
      gload_lds4(dp + o, &ring[rr][st][1][0]);
      gload_lds4(kp + o, &ring[rr][st][2][0]);
      gload_lds4(ap + o, &ring[rr][st][3][0]);
      gload_lds4(vp + o, &ring[rr][st][5][0]);
    }
  };

  issueL(0);
  for (int q = 0; q < CL / 8; ++q) {
    int rr = q & 1;
    // boundary: own loads for ring[rr] complete (stores issued after them may
    // remain outstanding: 16 y/u stores per phase -> vmcnt(16) for q>=1).
    if (q == 0) asm volatile("s_waitcnt vmcnt(0)" ::: "memory");
    else        asm volatile("s_waitcnt vmcnt(16)" ::: "memory");
    __builtin_amdgcn_sched_barrier(0);
    // fused prep on own slots (read raw k/a, write gated k / ain / bin)
#pragma unroll
    for (int k2 = 0; k2 < 2; ++k2) {
      int st = 2 * w + k2;
      float kraw = ring[rr][st][2][lane];
      float araw = ring[rr][st][3][lane];
      float kk = kraw * kkc;
      float ss = waveRedSum(kk * kk);
      float kkn = kk / fmaxf(sqrtf(ss), 1e-12f);
      ring[rr][st][2][lane] = kraw * (1.f + (araw - 1.f) * kac);
      ring[rr][st][3][lane] = -kkn;
      ring[rr][st][4][lane] = kkn * araw;
    }
    asm volatile("s_waitcnt lgkmcnt(0)" ::: "memory");
    __builtin_amdgcn_s_barrier();
    __builtin_amdgcn_sched_barrier(0);
    if (q + 1 < CL / 8) issueL(q + 1);   // ring[(q+1)&1]: consumed 2 phases ago
    __builtin_amdgcn_sched_barrier(0);   // pin loads before this phase's stores
#pragma unroll 2
    for (int st = 0; st < 8; ++st) {
      int t = q * 8 + st;
      float rv[16], dv[16], kv[16], av[16], bv[16];
#pragma unroll
      for (int qd = 0; qd < 4; qd++) {
        *(float4*)&rv[qd * 4] = *(const float4*)&ring[rr][st][0][col0 + qd * 4];
        *(float4*)&dv[qd * 4] = *(const float4*)&ring[rr][st][1][col0 + qd * 4];
        *(float4*)&kv[qd * 4] = *(const float4*)&ring[rr][st][2][col0 + qd * 4];
        *(float4*)&av[qd * 4] = *(const float4*)&ring[rr][st][3][col0 + qd * 4];
        *(float4*)&bv[qd * 4] = *(const float4*)&ring[rr][st][4][col0 + qd * 4];
      }
      float vi = ring[rr][st][5][row];
      float sa0 = 0.f, sa1 = 0.f, pa0 = 0.f, pa1 = 0.f;
#pragma unroll
      for (int jj = 0; jj < 8; jj++) {
        sa0 = fmaf(s[jj],     av[jj],     sa0);
        sa1 = fmaf(s[jj + 8], av[jj + 8], sa1);
        pa0 = fmaf(p[jj],     av[jj],     pa0);
        pa1 = fmaf(p[jj + 8], av[jj + 8], pa1);
      }
      float sa = sa0 + sa1;
      sa += __shfl_xor(sa, 16, 64); sa += __shfl_xor(sa, 32, 64);
      float pa = pa0 + pa1;
      pa += __shfl_xor(pa, 16, 64); pa += __shfl_xor(pa, 32, 64);
      float y0 = 0.f, y1 = 0.f, u0 = 0.f, u1 = 0.f;
#pragma unroll
      for (int jj = 0; jj < 8; jj++) {
        s[jj]     = fmaf(s[jj],     dv[jj],     fmaf(sa, bv[jj],     vi * kv[jj]));
        y0 = fmaf(s[jj], rv[jj], y0);
        p[jj]     = fmaf(p[jj],     dv[jj],     pa * bv[jj]);
        u0 = fmaf(p[jj], rv[jj], u0);
        s[jj + 8] = fmaf(s[jj + 8], dv[jj + 8], fmaf(sa, bv[jj + 8], vi * kv[jj + 8]));
        y1 = fmaf(s[jj + 8], rv[jj + 8], y1);
        p[jj + 8] = fmaf(p[jj + 8], dv[jj + 8], pa * bv[jj + 8]);
        u1 = fmaf(p[jj + 8], rv[jj + 8], u1);
      }
      float yv_ = y0 + y1;
      yv_ += __shfl_xor(yv_, 16, 64); yv_ += __shfl_xor(yv_, 32, 64);
      float uv_ = u0 + u1;
      uv_ += __shfl_xor(uv_, 16, 64); uv_ += __shfl_xor(uv_, 32, 64);
      if (quad == 0) {
        yp[cbase + (size_t)t * CC + row] = yv_;
        ubuf[((size_t)bid * CL + t) * 64 + row] = uv_;
      }
    }
  }

  float* zp = Zc + ((size_t)bid * 64 + row) * 64 + col0;
  float* pq = Pc + ((size_t)bid * 64 + row) * 64 + col0;
#pragma unroll
  for (int q4 = 0; q4 < 4; q4++) {
    *(float4*)&zp[q4 * 4] = make_float4(s[q4*4], s[q4*4+1], s[q4*4+2], s[q4*4+3]);
    *(float4*)&pq[q4 * 4] = make_float4(p[q4*4], p[q4*4+1], p[q4*4+2], p[q4*4+3]);
  }
}

// Phase 2 (56 blocks, 512 threads): Sin[c] = S; S = S*P_c + Z_c, sequential over c.
__global__ __launch_bounds__(512)
void scanp2_kernel(const float* __restrict__ Pc, const float* __restrict__ Zc,
                   float* __restrict__ Sin)
{
  int bh = blockIdx.x;
  int tid = threadIdx.x;
  int i = tid & 63, jg = tid >> 6, j0 = jg * 8;
  int sr = tid >> 3, sq = (tid & 7) * 8;
  __shared__ float S_lds[64][65];
  __shared__ __align__(16) float P_lds[64][68];

#pragma unroll
  for (int jj = 0; jj < 8; jj++) S_lds[i][j0 + jj] = 0.f;

  size_t b0 = (size_t)bh * NCH * 4096;
  float4 pr0 = *(const float4*)(Pc + b0 + (size_t)sr * 64 + sq);
  float4 pr1 = *(const float4*)(Pc + b0 + (size_t)sr * 64 + sq + 4);

  for (int c = 0; c < NCH; c++) {
    size_t bidc = (size_t)bh * NCH + c;
    *(float4*)&P_lds[sr][sq]     = pr0;
    *(float4*)&P_lds[sr][sq + 4] = pr1;
    if (c + 1 < NCH) {
      size_t bn = (bidc + 1) * 4096;
      pr0 = *(const float4*)(Pc + bn + (size_t)sr * 64 + sq);
      pr1 = *(const float4*)(Pc + bn + (size_t)sr * 64 + sq + 4);
    }
    float sv[8];
#pragma unroll
    for (int jj = 0; jj < 8; jj++) sv[jj] = S_lds[i][j0 + jj];
    {
      float4* sp_ = (float4*)(Sin + bidc * 4096 + (size_t)i * 64 + j0);
      sp_[0] = make_float4(sv[0], sv[1], sv[2], sv[3]);
      sp_[1] = make_float4(sv[4], sv[5], sv[6], sv[7]);
    }
    const float4* zp4 = (const float4*)(Zc + bidc * 4096 + (size_t)i * 64 + j0);
    float4 z0 = zp4[0], z1 = zp4[1];
    __syncthreads();
    float nv[8] = {0.f, 0.f, 0.f, 0.f, 0.f, 0.f, 0.f, 0.f};
    for (int m = 0; m < 64; m++) {
      float sm = S_lds[i][m];
#pragma unroll
      for (int jj = 0; jj < 8; jj++)
        nv[jj] = fmaf(sm, P_lds[m][j0 + jj], nv[jj]);
    }
    nv[0] += z0.x; nv[1] += z0.y; nv[2] += z0.z; nv[3] += z0.w;
    nv[4] += z1.x; nv[5] += z1.y; nv[6] += z1.z; nv[7] += z1.w;
    __syncthreads();
#pragma unroll
    for (int jj = 0; jj < 8; jj++) S_lds[i][j0 + jj] = nv[jj];
  }
}

// Phase 3 + groupnorm + rk*v + gate fused (896 blocks); k-gating applied inline
__global__ __launch_bounds__(256)
void scanp3gn_kernel(const float* __restrict__ Sin, const float* __restrict__ ubuf,
                     const float* __restrict__ y0p,
                     const float* __restrict__ rp, const float* __restrict__ kp,
                     const float* __restrict__ ap, const float* __restrict__ kag,
                     const float* __restrict__ vp, const float* __restrict__ gp,
                     const float* __restrict__ lnxw, const float* __restrict__ lnxb,
                     const float* __restrict__ rkco,
                     __hip_bfloat16* __restrict__ yout)
{
  int bid = blockIdx.x;
  int bh = bid >> 4, c = bid & 15;        // NCH=16
  int b = bh / HH, h = bh - b * HH;
  int tid = threadIdx.x, i = tid & 63, wv = tid >> 6;
  __shared__ float S_lds[64][65];
  __shared__ __align__(16) float U_lds[CL][64];
  {
    int r = tid >> 2, q = tid & 3;
    const float* src = Sin + (size_t)bid * 4096 + (size_t)r * 64 + q * 16;
#pragma unroll
    for (int jj = 0; jj < 16; jj++) S_lds[r][q * 16 + jj] = src[jj];
  }
  {
    int r = tid >> 3, q = tid & 7;
    const float4* us = (const float4*)(ubuf + (size_t)bid * (CL * 64) + (size_t)r * 64 + q * 8);
    float4* ud = (float4*)(&U_lds[r][q * 8]);
    ud[0] = us[0]; ud[1] = us[1];
  }
  __syncthreads();
  float sreg[64];
#pragma unroll
  for (int m = 0; m < 64; m++) sreg[m] = S_lds[i][m];
  int ch = h * NN + i;
  float lw = lnxw[ch], lb = lnxb[ch], rkc = rkco[ch], kaw = kag[ch];
  size_t rowbase = ((size_t)b * TT + (size_t)c * CL) * CC + ch;
#pragma unroll 1
  for (int tt = 0; tt < CL / 4; tt++) {
    int t = wv * (CL / 4) + tt;
    size_t off = rowbase + (size_t)t * CC;
    float a0 = 0.f, a1 = 0.f, a2 = 0.f, a3 = 0.f;
#pragma unroll
    for (int m4 = 0; m4 < 16; m4++) {
      float4 uu = *(const float4*)&U_lds[t][m4 * 4];
      a0 = fmaf(sreg[m4*4+0], uu.x, a0);
      a1 = fmaf(sreg[m4*4+1], uu.y, a1);
      a2 = fmaf(sreg[m4*4+2], uu.z, a2);
      a3 = fmaf(sreg[m4*4+3], uu.w, a3);
    }
    float yv = y0p[off] + (a0 + a1) + (a2 + a3);
    float s1 = waveRedSum(yv);
    float s2 = waveRedSum(yv * yv);
    float mean = s1 * (1.f / 64.f);
    float var  = s2 * (1.f / 64.f) - mean * mean;
    float norm = (yv - mean) * rsqrtf(var + 0.00064f);
    float rv = rp[off], kraw = kp[off], vv = vp[off], gv = gp[off];
    float aval = ap[off];
    float kg = kraw * (1.f + (aval - 1.f) * kaw);
    float rk = waveRedSum(rv * kg * rkc);
    yout[off] = __float2bfloat16((norm * lw + lb + rk * vv) * gv);
  }
}

// ---------------- host ----------------
extern "C" void kernel_launch(void* const* d_in, const int* in_sizes, int n_in,
                              void* d_out, int out_size, void* d_ws, size_t ws_size,
                              hipStream_t stream)
{
  const int*   idx    = (const int*)d_in[0];
  const float* emb    = (const float*)d_in[1];
  const float* ln0_w  = (const float*)d_in[2];
  const float* ln0_b  = (const float*)d_in[3];
  const float* ln1_w  = (const float*)d_in[4];
  const float* ln1_b  = (const float*)d_in[5];
  const float* ln2_w  = (const float*)d_in[6];
  const float* ln2_b  = (const float*)d_in[7];
  const float* x_r    = (const float*)d_in[8];
  const float* x_w    = (const float*)d_in[9];
  const float* x_k    = (const float*)d_in[10];
  const float* x_v    = (const float*)d_in[11];
  const float* x_a    = (const float*)d_in[12];
  const float* x_g    = (const float*)d_in[13];
  const float* w0     = (const float*)d_in[14];
  const float* w1     = (const float*)d_in[15];
  const float* w2     = (const float*)d_in[16];
  const float* a0     = (const float*)d_in[17];
  const float* a1     = (const float*)d_in[18];
  const float* a2     = (const float*)d_in[19];
  const float* v0     = (const float*)d_in[20];
  const float* v1     = (const float*)d_in[21];
  const float* v2     = (const float*)d_in[22];
  const float* g1     = (const float*)d_in[23];
  const float* g2     = (const float*)d_in[24];
  const float* k_k    = (const float*)d_in[25];
  const float* k_a    = (const float*)d_in[26];
  const float* r_k    = (const float*)d_in[27];
  const float* Wr     = (const float*)d_in[28];
  const float* Wk     = (const float*)d_in[29];
  const float* Wv     = (const float*)d_in[30];
  const float* Wo     = (const float*)d_in[31];
  const float* lnx_w  = (const float*)d_in[32];
  const float* lnx_b  = (const float*)d_in[33];
  const float* f_xk   = (const float*)d_in[34];
  const float* f_key  = (const float*)d_in[35];
  const float* f_val  = (const float*)d_in[36];
  const float* lnout_w = (const float*)d_in[37];
  const float* lnout_b = (const float*)d_in[38];
  const float* head_w  = (const float*)d_in[39];
  float* out = (float*)d_out;

  const size_t MC = (size_t)MM * CC;
  const size_t W2 = (size_t)CC * CC;
  const size_t WD = (size_t)DD * CC;
  const size_t WG = (size_t)192 * CC;
  const size_t WF = (size_t)FF4 * CC;
  float* ws   = (float*)d_ws;
  float* x      = ws;
  float* vfirst = x + MC;
  float* rb     = vfirst + MC;
  float* dcy    = rb + MC;       // rb+dcy contiguous: h_bf alias spans both
  float* kb     = dcy + MC;
  float* vb     = kb + MC;
  float* ab     = vb + MC;
  float* gb     = ab + MC;
  float* ainb   = gb + MC;       // unused (prep fused into scanrs)
  float* binb   = ainb + MC;     // unused
  float* yb     = binb + MC;
  float* ubuf   = yb + MC;       // 896*32*64 = MC
  float* Pcb    = ubuf + MC;     // 896*4096 = 2*MC
  float* Zcb    = Pcb + 2 * MC;
  float* Sinb   = Zcb + 2 * MC;
  float* fend   = Sinb + 2 * MC;
  (void)ainb; (void)binb;

  __hip_bfloat16* mixr_bf = (__hip_bfloat16*)fend;
  __hip_bfloat16* mixw_bf = mixr_bf + MC;
  __hip_bfloat16* mixk_bf = mixw_bf + MC;
  __hip_bfloat16* mixv_bf = mixk_bf + MC;
  __hip_bfloat16* mixa_bf = mixv_bf + MC;
  __hip_bfloat16* mixg_bf = mixa_bf + MC;
  // both-layer transposed weights
  __hip_bfloat16* WrT = mixg_bf + MC;        // 2*W2
  __hip_bfloat16* WkT = WrT + 2 * W2;
  __hip_bfloat16* WvT = WkT + 2 * W2;
  __hip_bfloat16* WoT = WvT + 2 * W2;
  __hip_bfloat16* fkT = WoT + 2 * W2;        // 2*WF
  __hip_bfloat16* fvT = fkT + 2 * WF;
  __hip_bfloat16* w1T = fvT + 2 * WF;        // 2*WD each
  __hip_bfloat16* a1T = w1T + 2 * WD;
  __hip_bfloat16* v1T = a1T + 2 * WD;
  __hip_bfloat16* w2T = v1T + 2 * WD;
  __hip_bfloat16* a2T = w2T + 2 * WD;
  __hip_bfloat16* v2T = a2T + 2 * WD;
  __hip_bfloat16* g1T = v2T + 2 * WD;        // 2*WG each
  __hip_bfloat16* g2T = g1T + 2 * WG;
  __hip_bfloat16* t64w = g2T + 2 * WG;       // [2048][64]
  __hip_bfloat16* t64a = t64w + (size_t)MM * 64;
  __hip_bfloat16* t64v = t64a + (size_t)MM * 64;
  __hip_bfloat16* t160 = t64v + (size_t)MM * 64;   // [2048][192]
  // aliases on dead f32 regions
  __hip_bfloat16* h_bf  = (__hip_bfloat16*)rb;     // [2048][3584] over rb+dcy
  __hip_bfloat16* yg_bf = (__hip_bfloat16*)ainb;   // [2048][896] (ainb now free)

  dim3 blk(256);

  // all weight transposes up front (both layers)
  convT_batch2<<<dim3(28, 28, 24), blk, 0, stream>>>(
      Wr, Wk, Wv, Wo, a1, a2, v1, v2, g1, g2, w1, w2,
      WrT, WkT, WvT, WoT, a1T, a2T, v1T, v2T, g1T, g2T, w1T, w2T);
  convT_big2<<<dim3(112, 28, 4), blk, 0, stream>>>(f_key, f_val, fkT, fvT);

  ln_kernel<<<MM, blk, 0, stream>>>(emb, idx, ln0_w, ln0_b, x);

  for (int l = 0; l < 2; l++) {
    lnmix6_kernel<<<MM, blk, 0, stream>>>(x, ln1_w + l * CC, ln1_b + l * CC,
        x_r + l * CC, x_w + l * CC, x_k + l * CC, x_v + l * CC, x_a + l * CC, x_g + l * CC,
        mixr_bf, mixw_bf, mixk_bf, mixv_bf, mixa_bf, mixg_bf);

    // r,k,v projections + LoRA stage-1, one launch (vfirst copy via epi in layer 0)
    gemm_rkv_lora1<<<dim3(7, 16, 4), blk, 0, stream>>>(
        mixr_bf, mixk_bf, mixv_bf, mixw_bf, mixa_bf, mixg_bf,
        WrT + l * W2, WkT + l * W2, WvT + l * W2,
        w1T + l * WD, a1T + l * WD, v1T + l * WD, g1T + l * WG,
        rb, kb, vb, vfirst, t64w, t64a, t64v, t160, l == 0 ? 1 : 0);

    // LoRA stage 2 (decay, sigmoid, g, v-gate) — BN=64, 224 blocks per slice
    lora2_batch<<<dim3(14, 16, l == 0 ? 3 : 4), blk, 0, stream>>>(
        t64w, t64a, t160, t64v,
        w2T + l * WD, a2T + l * WD, g2T + l * WG, v2T + l * WD,
        dcy, ab, gb, vb, w0 + l * CC, a0 + l * CC, v0 + l * CC, vfirst);

    // chunked scan with fused prep (+fused gn in phase 3)
    scanrs_kernel<<<BB * HH * NCH, blk, 0, stream>>>(rb, dcy, kb, ab, vb,
        k_k + l * CC, k_a + l * CC, yb, ubuf, Pcb, Zcb);
    scanp2_kernel<<<BB * HH, dim3(512), 0, stream>>>(Pcb, Zcb, Sinb);
    scanp3gn_kernel<<<BB * HH * NCH, blk, 0, stream>>>(Sinb, ubuf, yb, rb, kb,
        ab, k_a + l * CC, vb, gb,
        lnx_w + l * CC, lnx_b + l * CC, r_k + (size_t)l * CC, yg_bf);

    // x += (y*g) @ Wo   (BN=64 -> 224 blocks)
    gemm_ep<64><<<dim3(14, 16), blk, 0, stream>>>(yg_bf, WoT + l * W2, x, nullptr, CC, CC,
                                                  nullptr, nullptr, nullptr, CC, 1);

    // ---- channel mix ----
    lnmixc_kernel<<<MM, blk, 0, stream>>>(x, ln2_w + l * CC, ln2_b + l * CC,
                                          f_xk + l * CC, mixr_bf);
    gemm_ep<128><<<dim3(28, 16), blk, 0, stream>>>(mixr_bf, fkT + l * WF, nullptr, h_bf,
                                                   FF4, CC, nullptr, nullptr, nullptr, FF4, 2);
    gemm_ep<64><<<dim3(14, 16), blk, 0, stream>>>(h_bf, fvT + l * WF, x, nullptr, CC, FF4,
                                                  nullptr, nullptr, nullptr, CC, 1);
  }

  head_kernel<<<MM, blk, 0, stream>>>(x, lnout_w, lnout_b, head_w, out);
}